// Round 3
// baseline (315.134 us; speedup 1.0000x reference)
//
#include <hip/hip_runtime.h>
#include <hip/hip_bf16.h>
#include <cstdint>
#include <cstddef>

typedef __bf16 bf16_t;
typedef __attribute__((ext_vector_type(8))) __bf16 bf16x8;
typedef __attribute__((ext_vector_type(4))) __bf16 bf16x4;
typedef __attribute__((ext_vector_type(4))) float f32x4;

#define AS1 __attribute__((address_space(1)))
#define AS3 __attribute__((address_space(3)))

static constexpr int Bn = 2, Sn = 2048, En = 1024, Hn = 16, Dn = 64;

// ---------------------------------------------------------------- convert X
__global__ __launch_bounds__(256) void convert_f32_bf16(
    const float* __restrict__ in, bf16_t* __restrict__ out, int n) {
  int i = (blockIdx.x * 256 + threadIdx.x) * 4;
  if (i < n) {
    float4 v = *(const float4*)(in + i);
    bf16x4 o;
    o[0] = (bf16_t)v.x; o[1] = (bf16_t)v.y; o[2] = (bf16_t)v.z; o[3] = (bf16_t)v.w;
    *(bf16x4*)(out + i) = o;
  }
}

// ------------------------------------------- transpose fp32 [R][C] -> bf16 [C][R]
__global__ __launch_bounds__(256) void transpose_conv(
    const float* __restrict__ in, bf16_t* __restrict__ out, int R, int C) {
  __shared__ float tile[32][33];
  int bx = blockIdx.x * 32, by = blockIdx.y * 32;
  int tx = threadIdx.x & 31, ty = threadIdx.x >> 5;  // ty 0..7
#pragma unroll
  for (int i = 0; i < 32; i += 8)
    tile[ty + i][tx] = in[(size_t)(by + ty + i) * C + bx + tx];
  __syncthreads();
#pragma unroll
  for (int i = 0; i < 32; i += 8)
    out[(size_t)(bx + ty + i) * R + by + tx] = (bf16_t)tile[tx][ty + i];
}

// -------------------------------- V [bh][S][64] -> Vt [bh][64][S]  (bf16)
__global__ __launch_bounds__(256) void transpose_v(
    const bf16_t* __restrict__ V, bf16_t* __restrict__ Vt) {
  __shared__ ushort tile[64][65];
  int bh = blockIdx.y, s0 = blockIdx.x * 64;
  int t = threadIdx.x;
  const ushort* src = (const ushort*)(V + ((size_t)bh * Sn + s0) * 64);
#pragma unroll
  for (int p = 0; p < 4; ++p) {
    int s = p * 16 + (t >> 4);
    int c = (t & 15) * 4;
    ushort4 v = *(const ushort4*)(src + (size_t)s * 64 + c);
    tile[s][c] = v.x; tile[s][c + 1] = v.y; tile[s][c + 2] = v.z; tile[s][c + 3] = v.w;
  }
  __syncthreads();
  ushort* dst = (ushort*)(Vt + ((size_t)bh * 64) * Sn + s0);
#pragma unroll
  for (int p = 0; p < 4; ++p) {
    int d = p * 16 + (t >> 4);
    int c = (t & 15) * 4;  // s offset within tile
    ushort4 v;
    v.x = tile[c][d]; v.y = tile[c + 1][d]; v.z = tile[c + 2][d]; v.w = tile[c + 3][d];
    *(ushort4*)(dst + (size_t)d * Sn + c) = v;
  }
}

// ---------------------------------------------------------------- GEMM core
// C = A[M][K] · Bt[N][K]^T. 128x128 tile, BK=32, 256 threads (2x2 waves of
// 64x64). global_load_lds width-16 staging; chunk XOR-swizzle (rule #21):
// LDS[row][chunk] holds global chunk (chunk ^ (row&3)); read applies same XOR.
template <int K_>
__device__ __forceinline__ void gemm_core(
    const bf16_t* __restrict__ A, const bf16_t* __restrict__ Bt,
    f32x4 (&acc)[4][4], int& col0, int& row0) {
  __shared__ bf16_t As[2][128 * 32];
  __shared__ bf16_t Bs[2][128 * 32];
  const int tid = threadIdx.x, lane = tid & 63, wid = tid >> 6;
  const int wm = wid >> 1, wn = wid & 1;
  const int m0 = blockIdx.y * 128, n0 = blockIdx.x * 128;
  const int KT = K_ / 32;

  auto stage = [&](bf16_t* as, bf16_t* bs, int kt) {
    int csw = ((lane & 3) ^ ((lane >> 2) & 3)) * 8;
#pragma unroll
    for (int j = 0; j < 2; ++j) {
      int r0 = wid * 32 + j * 16;
      const bf16_t* ga = A + (size_t)(m0 + r0 + (lane >> 2)) * K_ + kt * 32 + csw;
      __builtin_amdgcn_global_load_lds((const AS1 void*)ga, (AS3 void*)(as + r0 * 32), 16, 0, 0);
      const bf16_t* gb = Bt + (size_t)(n0 + r0 + (lane >> 2)) * K_ + kt * 32 + csw;
      __builtin_amdgcn_global_load_lds((const AS1 void*)gb, (AS3 void*)(bs + r0 * 32), 16, 0, 0);
    }
  };
  auto compute = [&](const bf16_t* as, const bf16_t* bs) {
    bf16x8 af[4], bfr[4];
    uint32_t swz = (uint32_t)(((lane >> 4) ^ (lane & 3)) << 4);
#pragma unroll
    for (int mi = 0; mi < 4; ++mi) {
      uint32_t row = (uint32_t)(wm * 64 + mi * 16 + (lane & 15));
      af[mi] = *(const bf16x8*)((const char*)as + row * 64 + swz);
    }
#pragma unroll
    for (int ni = 0; ni < 4; ++ni) {
      uint32_t row = (uint32_t)(wn * 64 + ni * 16 + (lane & 15));
      bfr[ni] = *(const bf16x8*)((const char*)bs + row * 64 + swz);
    }
#pragma unroll
    for (int mi = 0; mi < 4; ++mi)
#pragma unroll
      for (int ni = 0; ni < 4; ++ni)
        acc[mi][ni] = __builtin_amdgcn_mfma_f32_16x16x32_bf16(af[mi], bfr[ni], acc[mi][ni], 0, 0, 0);
  };

  stage(As[0], Bs[0], 0);
  __syncthreads();
  int cur = 0;
  for (int kt = 0; kt < KT - 1; ++kt) {
    stage(As[cur ^ 1], Bs[cur ^ 1], kt + 1);
    compute(As[cur], Bs[cur]);
    __syncthreads();
    cur ^= 1;
  }
  compute(As[cur], Bs[cur]);
  col0 = n0 + wn * 64 + (lane & 15);
  row0 = m0 + wm * 64 + ((lane >> 4) << 2);
}

__global__ __launch_bounds__(256) void gemm_qkv(
    const bf16_t* __restrict__ A, const bf16_t* __restrict__ Bt,
    const float* __restrict__ bias, bf16_t* __restrict__ Qb,
    bf16_t* __restrict__ Kb, bf16_t* __restrict__ Vb) {
  f32x4 acc[4][4] = {};
  int col0, row0;
  gemm_core<1024>(A, Bt, acc, col0, row0);
#pragma unroll
  for (int ni = 0; ni < 4; ++ni) {
    int n = col0 + ni * 16;
    float bv = bias[n];
    int which = n >> 10, nn = n & 1023;
    int h = nn >> 6, dd = nn & 63;
    bf16_t* dst = which == 0 ? Qb : (which == 1 ? Kb : Vb);
    float scl = which == 0 ? 0.125f : 1.0f;  // fold 1/sqrt(64) into Q
#pragma unroll
    for (int mi = 0; mi < 4; ++mi)
#pragma unroll
      for (int i = 0; i < 4; ++i) {
        int m = row0 + mi * 16 + i;
        int b = m >> 11, s = m & 2047;
        float v = (acc[mi][ni][i] + bv) * scl;
        dst[(((size_t)b * Hn + h) * Sn + s) * 64 + dd] = (bf16_t)v;
      }
  }
}

__global__ __launch_bounds__(256) void gemm_out(
    const bf16_t* __restrict__ A, const bf16_t* __restrict__ Bt,
    const float* __restrict__ bias, float* __restrict__ out) {
  f32x4 acc[4][4] = {};
  int col0, row0;
  gemm_core<1024>(A, Bt, acc, col0, row0);
#pragma unroll
  for (int ni = 0; ni < 4; ++ni) {
    int n = col0 + ni * 16;
    float bv = bias[n];
#pragma unroll
    for (int mi = 0; mi < 4; ++mi)
#pragma unroll
      for (int i = 0; i < 4; ++i) {
        int m = row0 + mi * 16 + i;
        out[(size_t)m * En + n] = acc[mi][ni][i] + bv;
      }
  }
}

// -------------------------------------------------------- flash attention fwd
// grid (S/64, B*H); 4 waves x 16 q-rows; KVBLK=64; causal (mask analytic).
__global__ __launch_bounds__(256) void attn_fwd(
    const bf16_t* __restrict__ Qb, const bf16_t* __restrict__ Kb,
    const bf16_t* __restrict__ Vt, bf16_t* __restrict__ AO) {
  __shared__ bf16_t Ks[64 * 64];
  __shared__ bf16_t Vs[64 * 64];
  __shared__ bf16_t Ps[4][16 * 64];
  const int tid = threadIdx.x, lane = tid & 63, wid = tid >> 6;
  const int bh = blockIdx.y;
  const int q0 = blockIdx.x * 64;
  const int qb = q0 + wid * 16;

  bf16x8 aq[2];
  {
    const bf16_t* qp = Qb + ((size_t)bh * Sn + qb + (lane & 15)) * 64 + ((lane >> 4) << 3);
    aq[0] = *(const bf16x8*)qp;
    aq[1] = *(const bf16x8*)(qp + 32);
  }
  f32x4 O[4] = {};
  float m_run[4], l_run[4];
#pragma unroll
  for (int i = 0; i < 4; ++i) { m_run[i] = -1e30f; l_run[i] = 0.f; }

  const int nt = q0 / 64 + 1;
  for (int t = 0; t < nt; ++t) {
    // stage K tile [64 kv][64 d] and Vt tile [64 d][64 kv], XOR-swizzled rows
    {
      int rr = tid >> 3, c = tid & 7;
#pragma unroll
      for (int p = 0; p < 2; ++p) {
        int r = rr + p * 32;
        uint32_t off = (uint32_t)(r * 128 + c * 16) ^ (uint32_t)((r & 7) << 4);
        const bf16_t* gk = Kb + ((size_t)bh * Sn + t * 64 + r) * 64 + c * 8;
        *(bf16x8*)((char*)Ks + off) = *(const bf16x8*)gk;
        const bf16_t* gv = Vt + ((size_t)bh * 64 + r) * Sn + t * 64 + c * 8;
        *(bf16x8*)((char*)Vs + off) = *(const bf16x8*)gv;
      }
    }
    __syncthreads();
    // QK^T : S[16 q][64 kv]
    f32x4 sc[4];
#pragma unroll
    for (int ni = 0; ni < 4; ++ni) {
      int kvr = ni * 16 + (lane & 15);
      uint32_t o0 = (uint32_t)(kvr * 128 + ((lane >> 4) << 4)) ^ (uint32_t)((kvr & 7) << 4);
      uint32_t o1 = (uint32_t)(kvr * 128 + 64 + ((lane >> 4) << 4)) ^ (uint32_t)((kvr & 7) << 4);
      bf16x8 b0 = *(const bf16x8*)((const char*)Ks + o0);
      bf16x8 b1 = *(const bf16x8*)((const char*)Ks + o1);
      f32x4 z = {};
      z = __builtin_amdgcn_mfma_f32_16x16x32_bf16(aq[0], b0, z, 0, 0, 0);
      sc[ni] = __builtin_amdgcn_mfma_f32_16x16x32_bf16(aq[1], b1, z, 0, 0, 0);
    }
    if (t == nt - 1) {  // diagonal tile: causal mask
#pragma unroll
      for (int ni = 0; ni < 4; ++ni) {
        int kv = t * 64 + ni * 16 + (lane & 15);
#pragma unroll
        for (int i = 0; i < 4; ++i) {
          int q = qb + ((lane >> 4) << 2) + i;
          if (kv > q) sc[ni][i] = -1e30f;
        }
      }
    }
    // online softmax (row i lives at q = qb + (lane>>4)*4 + i)
    float mt[4];
#pragma unroll
    for (int i = 0; i < 4; ++i) {
      float v = fmaxf(fmaxf(sc[0][i], sc[1][i]), fmaxf(sc[2][i], sc[3][i]));
      v = fmaxf(v, __shfl_xor(v, 1));
      v = fmaxf(v, __shfl_xor(v, 2));
      v = fmaxf(v, __shfl_xor(v, 4));
      v = fmaxf(v, __shfl_xor(v, 8));
      mt[i] = v;
    }
    float scale[4], rs[4];
#pragma unroll
    for (int i = 0; i < 4; ++i) {
      float mn = fmaxf(m_run[i], mt[i]);
      scale[i] = __expf(m_run[i] - mn);
      m_run[i] = mn;
      rs[i] = 0.f;
    }
    char* pw = (char*)Ps[wid];
#pragma unroll
    for (int ni = 0; ni < 4; ++ni)
#pragma unroll
      for (int i = 0; i < 4; ++i) {
        float p = __expf(sc[ni][i] - m_run[i]);
        rs[i] += p;
        int r = ((lane >> 4) << 2) + i;
        uint32_t off = (uint32_t)(r * 128 + (ni * 16 + (lane & 15)) * 2) ^ (uint32_t)((r & 7) << 4);
        *(bf16_t*)(pw + off) = (bf16_t)p;
      }
#pragma unroll
    for (int i = 0; i < 4; ++i) {
      float v = rs[i];
      v += __shfl_xor(v, 1);
      v += __shfl_xor(v, 2);
      v += __shfl_xor(v, 4);
      v += __shfl_xor(v, 8);
      l_run[i] = l_run[i] * scale[i] + v;
    }
#pragma unroll
    for (int n2 = 0; n2 < 4; ++n2)
#pragma unroll
      for (int i = 0; i < 4; ++i) O[n2][i] *= scale[i];
    asm volatile("s_waitcnt lgkmcnt(0)" ::: "memory");
    __builtin_amdgcn_sched_barrier(0);
    // PV : O += P[16 q][64 kv] x V[64 kv][64 d]
    bf16x8 pa[2];
    {
      int r = lane & 15;
      uint32_t o0 = (uint32_t)(r * 128 + ((lane >> 4) << 4)) ^ (uint32_t)((r & 7) << 4);
      uint32_t o1 = (uint32_t)(r * 128 + 64 + ((lane >> 4) << 4)) ^ (uint32_t)((r & 7) << 4);
      pa[0] = *(const bf16x8*)((const char*)pw + o0);
      pa[1] = *(const bf16x8*)((const char*)pw + o1);
    }
#pragma unroll
    for (int n2 = 0; n2 < 4; ++n2) {
      int dr = n2 * 16 + (lane & 15);
      uint32_t o0 = (uint32_t)(dr * 128 + ((lane >> 4) << 4)) ^ (uint32_t)((dr & 7) << 4);
      uint32_t o1 = (uint32_t)(dr * 128 + 64 + ((lane >> 4) << 4)) ^ (uint32_t)((dr & 7) << 4);
      bf16x8 v0 = *(const bf16x8*)((const char*)Vs + o0);
      bf16x8 v1 = *(const bf16x8*)((const char*)Vs + o1);
      O[n2] = __builtin_amdgcn_mfma_f32_16x16x32_bf16(pa[0], v0, O[n2], 0, 0, 0);
      O[n2] = __builtin_amdgcn_mfma_f32_16x16x32_bf16(pa[1], v1, O[n2], 0, 0, 0);
    }
    __syncthreads();
  }
  // epilogue: AO[b][s][h*64+d] bf16
  int b = bh >> 4, h = bh & 15;
#pragma unroll
  for (int i = 0; i < 4; ++i) {
    float inv = 1.0f / l_run[i];
    int q = qb + ((lane >> 4) << 2) + i;
#pragma unroll
    for (int n2 = 0; n2 < 4; ++n2) {
      int d = n2 * 16 + (lane & 15);
      AO[((size_t)b * Sn + q) * En + h * 64 + d] = (bf16_t)(O[n2][i] * inv);
    }
  }
}

// ---------------------------------------------------------------- launch
extern "C" void kernel_launch(void* const* d_in, const int* in_sizes, int n_in,
                              void* d_out, int out_size, void* d_ws, size_t ws_size,
                              hipStream_t stream) {
  const float* X     = (const float*)d_in[0];
  // d_in[1] = mask (causal; applied analytically)
  const float* W_qkv = (const float*)d_in[2];
  const float* b_qkv = (const float*)d_in[3];
  const float* W_o   = (const float*)d_in[4];
  const float* b_o   = (const float*)d_in[5];
  float* out = (float*)d_out;

  char* ws = (char*)d_ws;
  bf16_t* Xb  = (bf16_t*)(ws);
  bf16_t* WqT = (bf16_t*)(ws + 8388608);
  bf16_t* WoT = (bf16_t*)(ws + 14680064);
  bf16_t* Qb  = (bf16_t*)(ws + 16777216);
  bf16_t* Kb  = (bf16_t*)(ws + 25165824);
  bf16_t* Vb  = (bf16_t*)(ws + 33554432);
  bf16_t* Vt  = (bf16_t*)(ws + 41943040);
  bf16_t* AO  = (bf16_t*)(ws + 50331648);

  convert_f32_bf16<<<4096, 256, 0, stream>>>(X, Xb, Bn * Sn * En);
  transpose_conv<<<dim3(96, 32), 256, 0, stream>>>(W_qkv, WqT, 1024, 3072);
  transpose_conv<<<dim3(32, 32), 256, 0, stream>>>(W_o, WoT, 1024, 1024);
  gemm_qkv<<<dim3(24, 32), 256, 0, stream>>>(Xb, WqT, b_qkv, Qb, Kb, Vb);
  transpose_v<<<dim3(32, 32), 256, 0, stream>>>(Vb, Vt);
  attn_fwd<<<dim3(32, 32), 256, 0, stream>>>(Qb, Kb, Vt, AO);
  gemm_out<<<dim3(8, 32), 256, 0, stream>>>(AO, WoT, b_o, out);
}

// Round 4
// 265.313 us; speedup vs baseline: 1.1878x; 1.1878x over previous
//
#include <hip/hip_runtime.h>
#include <hip/hip_bf16.h>
#include <cstdint>
#include <cstddef>

typedef __bf16 bf16_t;
typedef __attribute__((ext_vector_type(8))) __bf16 bf16x8;
typedef __attribute__((ext_vector_type(4))) __bf16 bf16x4;
typedef __attribute__((ext_vector_type(4))) float f32x4;

#define AS1 __attribute__((address_space(1)))
#define AS3 __attribute__((address_space(3)))

static constexpr int Bn = 2, Sn = 2048, En = 1024, Hn = 16, Dn = 64;

// ---------------------------------------------------------------- convert X
__global__ __launch_bounds__(256) void convert_f32_bf16(
    const float* __restrict__ in, bf16_t* __restrict__ out, int n) {
  int i = (blockIdx.x * 256 + threadIdx.x) * 4;
  if (i < n) {
    float4 v = *(const float4*)(in + i);
    bf16x4 o;
    o[0] = (bf16_t)v.x; o[1] = (bf16_t)v.y; o[2] = (bf16_t)v.z; o[3] = (bf16_t)v.w;
    *(bf16x4*)(out + i) = o;
  }
}

// ------------------------------------------- transpose fp32 [R][C] -> bf16 [C][R]
__global__ __launch_bounds__(256) void transpose_conv(
    const float* __restrict__ in, bf16_t* __restrict__ out, int R, int C) {
  __shared__ float tile[32][33];
  int bx = blockIdx.x * 32, by = blockIdx.y * 32;
  int tx = threadIdx.x & 31, ty = threadIdx.x >> 5;  // ty 0..7
#pragma unroll
  for (int i = 0; i < 32; i += 8)
    tile[ty + i][tx] = in[(size_t)(by + ty + i) * C + bx + tx];
  __syncthreads();
#pragma unroll
  for (int i = 0; i < 32; i += 8)
    out[(size_t)(bx + ty + i) * R + by + tx] = (bf16_t)tile[tx][ty + i];
}

// -------------------------------- V [bh][S][64] -> Vt [bh][64][S]  (bf16)
__global__ __launch_bounds__(256) void transpose_v(
    const bf16_t* __restrict__ V, bf16_t* __restrict__ Vt) {
  __shared__ ushort tile[64][65];
  int bh = blockIdx.y, s0 = blockIdx.x * 64;
  int t = threadIdx.x;
  const ushort* src = (const ushort*)(V + ((size_t)bh * Sn + s0) * 64);
#pragma unroll
  for (int p = 0; p < 4; ++p) {
    int s = p * 16 + (t >> 4);
    int c = (t & 15) * 4;
    ushort4 v = *(const ushort4*)(src + (size_t)s * 64 + c);
    tile[s][c] = v.x; tile[s][c + 1] = v.y; tile[s][c + 2] = v.z; tile[s][c + 3] = v.w;
  }
  __syncthreads();
  ushort* dst = (ushort*)(Vt + ((size_t)bh * 64) * Sn + s0);
#pragma unroll
  for (int p = 0; p < 4; ++p) {
    int d = p * 16 + (t >> 4);
    int c = (t & 15) * 4;  // s offset within tile
    ushort4 v;
    v.x = tile[c][d]; v.y = tile[c + 1][d]; v.z = tile[c + 2][d]; v.w = tile[c + 3][d];
    *(ushort4*)(dst + (size_t)d * Sn + c) = v;
  }
}

// ---------------------------------------------------------------- GEMM core
// C = A[M][K] · Bt[N][K]^T. 128x128 tile, BK=32, 256 threads (2x2 waves of
// 64x64). global_load_lds width-16 staging; chunk XOR-swizzle (rule #21):
// LDS[row][chunk] holds global chunk (chunk ^ (row&3)); read applies same XOR.
template <int K_>
__device__ __forceinline__ void gemm_core(
    const bf16_t* __restrict__ A, const bf16_t* __restrict__ Bt,
    f32x4 (&acc)[4][4], int& col0, int& row0) {
  __shared__ bf16_t As[2][128 * 32];
  __shared__ bf16_t Bs[2][128 * 32];
  const int tid = threadIdx.x, lane = tid & 63, wid = tid >> 6;
  const int wm = wid >> 1, wn = wid & 1;
  const int m0 = blockIdx.y * 128, n0 = blockIdx.x * 128;
  const int KT = K_ / 32;

  auto stage = [&](bf16_t* as, bf16_t* bs, int kt) {
    int csw = ((lane & 3) ^ ((lane >> 2) & 3)) * 8;
#pragma unroll
    for (int j = 0; j < 2; ++j) {
      int r0 = wid * 32 + j * 16;
      const bf16_t* ga = A + (size_t)(m0 + r0 + (lane >> 2)) * K_ + kt * 32 + csw;
      __builtin_amdgcn_global_load_lds((const AS1 void*)ga, (AS3 void*)(as + r0 * 32), 16, 0, 0);
      const bf16_t* gb = Bt + (size_t)(n0 + r0 + (lane >> 2)) * K_ + kt * 32 + csw;
      __builtin_amdgcn_global_load_lds((const AS1 void*)gb, (AS3 void*)(bs + r0 * 32), 16, 0, 0);
    }
  };
  auto compute = [&](const bf16_t* as, const bf16_t* bs) {
    bf16x8 af[4], bfr[4];
    uint32_t swz = (uint32_t)(((lane >> 4) ^ (lane & 3)) << 4);
#pragma unroll
    for (int mi = 0; mi < 4; ++mi) {
      uint32_t row = (uint32_t)(wm * 64 + mi * 16 + (lane & 15));
      af[mi] = *(const bf16x8*)((const char*)as + row * 64 + swz);
    }
#pragma unroll
    for (int ni = 0; ni < 4; ++ni) {
      uint32_t row = (uint32_t)(wn * 64 + ni * 16 + (lane & 15));
      bfr[ni] = *(const bf16x8*)((const char*)bs + row * 64 + swz);
    }
#pragma unroll
    for (int mi = 0; mi < 4; ++mi)
#pragma unroll
      for (int ni = 0; ni < 4; ++ni)
        acc[mi][ni] = __builtin_amdgcn_mfma_f32_16x16x32_bf16(af[mi], bfr[ni], acc[mi][ni], 0, 0, 0);
  };

  stage(As[0], Bs[0], 0);
  __syncthreads();
  int cur = 0;
  for (int kt = 0; kt < KT - 1; ++kt) {
    stage(As[cur ^ 1], Bs[cur ^ 1], kt + 1);
    compute(As[cur], Bs[cur]);
    __syncthreads();
    cur ^= 1;
  }
  compute(As[cur], Bs[cur]);
  col0 = n0 + wn * 64 + (lane & 15);
  row0 = m0 + wm * 64 + ((lane >> 4) << 2);
}

__global__ __launch_bounds__(256) void gemm_qkv(
    const bf16_t* __restrict__ A, const bf16_t* __restrict__ Bt,
    const float* __restrict__ bias, bf16_t* __restrict__ Qb,
    bf16_t* __restrict__ Kb, bf16_t* __restrict__ Vb) {
  f32x4 acc[4][4] = {};
  int col0, row0;
  gemm_core<1024>(A, Bt, acc, col0, row0);
#pragma unroll
  for (int ni = 0; ni < 4; ++ni) {
    int n = col0 + ni * 16;
    float bv = bias[n];
    int which = n >> 10, nn = n & 1023;
    int h = nn >> 6, dd = nn & 63;
    bf16_t* dst = which == 0 ? Qb : (which == 1 ? Kb : Vb);
    float scl = which == 0 ? 0.125f : 1.0f;  // fold 1/sqrt(64) into Q
#pragma unroll
    for (int mi = 0; mi < 4; ++mi)
#pragma unroll
      for (int i = 0; i < 4; ++i) {
        int m = row0 + mi * 16 + i;
        int b = m >> 11, s = m & 2047;
        float v = (acc[mi][ni][i] + bv) * scl;
        dst[(((size_t)b * Hn + h) * Sn + s) * 64 + dd] = (bf16_t)v;
      }
  }
}

__global__ __launch_bounds__(256) void gemm_out(
    const bf16_t* __restrict__ A, const bf16_t* __restrict__ Bt,
    const float* __restrict__ bias, float* __restrict__ out) {
  f32x4 acc[4][4] = {};
  int col0, row0;
  gemm_core<1024>(A, Bt, acc, col0, row0);
#pragma unroll
  for (int ni = 0; ni < 4; ++ni) {
    int n = col0 + ni * 16;
    float bv = bias[n];
#pragma unroll
    for (int mi = 0; mi < 4; ++mi)
#pragma unroll
      for (int i = 0; i < 4; ++i) {
        int m = row0 + mi * 16 + i;
        out[(size_t)m * En + n] = acc[mi][ni][i] + bv;
      }
  }
}

// -------------------------------------------------------- flash attention fwd
// grid (32, B*H); q_tile = x ^ y (work balance); 4 waves x 16 q-rows; KVBLK=64.
// K/V double-buffered, staged via global_load_lds w16 with pre-swizzled global
// source (physical chunk cp of row r holds logical chunk cp^(r&7) — matches
// the read-side XOR byte swizzle). One barrier per tile; prefetch t+1 under
// compute of t.
__global__ __launch_bounds__(256) void attn_fwd(
    const bf16_t* __restrict__ Qb, const bf16_t* __restrict__ Kb,
    const bf16_t* __restrict__ Vt, bf16_t* __restrict__ AO) {
  __shared__ bf16_t Ks[2][64 * 64];
  __shared__ bf16_t Vs[2][64 * 64];
  __shared__ bf16_t Ps[4][16 * 64];
  const int tid = threadIdx.x, lane = tid & 63, wid = tid >> 6;
  const int bh = blockIdx.y;
  const int q_tile = (int)(blockIdx.x ^ blockIdx.y) & 31;
  const int q0 = q_tile * 64;
  const int qb = q0 + wid * 16;

  bf16x8 aq[2];
  {
    const bf16_t* qp = Qb + ((size_t)bh * Sn + qb + (lane & 15)) * 64 + ((lane >> 4) << 3);
    aq[0] = *(const bf16x8*)qp;
    aq[1] = *(const bf16x8*)(qp + 32);
  }
  f32x4 O[4] = {};
  float m_run[4], l_run[4];
#pragma unroll
  for (int i = 0; i < 4; ++i) { m_run[i] = -1e30f; l_run[i] = 0.f; }

  // stage K rows (kv) and V rows (d) for tile t into buf: wave w covers rows
  // w*16..w*16+15 via 2 x global_load_lds (each covers 8 rows, 16B/lane).
  const int rl = lane >> 3;     // row within 8-row group
  const int cp = lane & 7;      // physical 16B chunk
  auto issueKV = [&](int buf, int t) {
#pragma unroll
    for (int j = 0; j < 2; ++j) {
      int r = wid * 16 + j * 8 + rl;
      int sc = cp ^ (r & 7);    // source logical chunk (pre-swizzle)
      const bf16_t* gk = Kb + (((size_t)bh * Sn + t * 64 + r) << 6) + (sc << 3);
      __builtin_amdgcn_global_load_lds((const AS1 void*)gk,
          (AS3 void*)(&Ks[buf][wid * 1024 + j * 512]), 16, 0, 0);
      const bf16_t* gv = Vt + ((size_t)bh * 64 + r) * Sn + t * 64 + (sc << 3);
      __builtin_amdgcn_global_load_lds((const AS1 void*)gv,
          (AS3 void*)(&Vs[buf][wid * 1024 + j * 512]), 16, 0, 0);
    }
  };

  const int nt = q_tile + 1;
  issueKV(0, 0);
  for (int t = 0; t < nt; ++t) {
    const int cur = t & 1;
    asm volatile("s_waitcnt vmcnt(0)" ::: "memory");
    __syncthreads();
    if (t + 1 < nt) issueKV(cur ^ 1, t + 1);
    const char* ksb = (const char*)Ks[cur];
    const char* vsb = (const char*)Vs[cur];
    // QK^T : S[16 q][64 kv]
    f32x4 sc[4];
#pragma unroll
    for (int ni = 0; ni < 4; ++ni) {
      int kvr = ni * 16 + (lane & 15);
      uint32_t o0 = (uint32_t)(kvr * 128 + ((lane >> 4) << 4)) ^ (uint32_t)((kvr & 7) << 4);
      uint32_t o1 = (uint32_t)(kvr * 128 + 64 + ((lane >> 4) << 4)) ^ (uint32_t)((kvr & 7) << 4);
      bf16x8 b0 = *(const bf16x8*)(ksb + o0);
      bf16x8 b1 = *(const bf16x8*)(ksb + o1);
      f32x4 z = {};
      z = __builtin_amdgcn_mfma_f32_16x16x32_bf16(aq[0], b0, z, 0, 0, 0);
      sc[ni] = __builtin_amdgcn_mfma_f32_16x16x32_bf16(aq[1], b1, z, 0, 0, 0);
    }
    if (t == nt - 1) {  // diagonal tile: causal mask
#pragma unroll
      for (int ni = 0; ni < 4; ++ni) {
        int kv = t * 64 + ni * 16 + (lane & 15);
#pragma unroll
        for (int i = 0; i < 4; ++i) {
          int q = qb + ((lane >> 4) << 2) + i;
          if (kv > q) sc[ni][i] = -1e30f;
        }
      }
    }
    // online softmax (row i lives at q = qb + (lane>>4)*4 + i)
    float mt[4];
#pragma unroll
    for (int i = 0; i < 4; ++i) {
      float v = fmaxf(fmaxf(sc[0][i], sc[1][i]), fmaxf(sc[2][i], sc[3][i]));
      v = fmaxf(v, __shfl_xor(v, 1));
      v = fmaxf(v, __shfl_xor(v, 2));
      v = fmaxf(v, __shfl_xor(v, 4));
      v = fmaxf(v, __shfl_xor(v, 8));
      mt[i] = v;
    }
    float scale[4], rs[4];
#pragma unroll
    for (int i = 0; i < 4; ++i) {
      float mn = fmaxf(m_run[i], mt[i]);
      scale[i] = __expf(m_run[i] - mn);
      m_run[i] = mn;
      rs[i] = 0.f;
    }
    char* pw = (char*)Ps[wid];
#pragma unroll
    for (int ni = 0; ni < 4; ++ni)
#pragma unroll
      for (int i = 0; i < 4; ++i) {
        float p = __expf(sc[ni][i] - m_run[i]);
        rs[i] += p;
        int r = ((lane >> 4) << 2) + i;
        uint32_t off = (uint32_t)(r * 128 + (ni * 16 + (lane & 15)) * 2) ^ (uint32_t)((r & 7) << 4);
        *(bf16_t*)(pw + off) = (bf16_t)p;
      }
#pragma unroll
    for (int i = 0; i < 4; ++i) {
      float v = rs[i];
      v += __shfl_xor(v, 1);
      v += __shfl_xor(v, 2);
      v += __shfl_xor(v, 4);
      v += __shfl_xor(v, 8);
      l_run[i] = l_run[i] * scale[i] + v;
    }
#pragma unroll
    for (int n2 = 0; n2 < 4; ++n2)
#pragma unroll
      for (int i = 0; i < 4; ++i) O[n2][i] *= scale[i];
    asm volatile("s_waitcnt lgkmcnt(0)" ::: "memory");
    __builtin_amdgcn_sched_barrier(0);
    // PV : O += P[16 q][64 kv] x V[64 kv][64 d]
    bf16x8 pa[2];
    {
      int r = lane & 15;
      uint32_t o0 = (uint32_t)(r * 128 + ((lane >> 4) << 4)) ^ (uint32_t)((r & 7) << 4);
      uint32_t o1 = (uint32_t)(r * 128 + 64 + ((lane >> 4) << 4)) ^ (uint32_t)((r & 7) << 4);
      pa[0] = *(const bf16x8*)((const char*)pw + o0);
      pa[1] = *(const bf16x8*)((const char*)pw + o1);
    }
#pragma unroll
    for (int n2 = 0; n2 < 4; ++n2) {
      int dr = n2 * 16 + (lane & 15);
      uint32_t o0 = (uint32_t)(dr * 128 + ((lane >> 4) << 4)) ^ (uint32_t)((dr & 7) << 4);
      uint32_t o1 = (uint32_t)(dr * 128 + 64 + ((lane >> 4) << 4)) ^ (uint32_t)((dr & 7) << 4);
      bf16x8 v0 = *(const bf16x8*)(vsb + o0);
      bf16x8 v1 = *(const bf16x8*)(vsb + o1);
      O[n2] = __builtin_amdgcn_mfma_f32_16x16x32_bf16(pa[0], v0, O[n2], 0, 0, 0);
      O[n2] = __builtin_amdgcn_mfma_f32_16x16x32_bf16(pa[1], v1, O[n2], 0, 0, 0);
    }
  }
  // epilogue: AO[b][s][h*64+d] bf16
  int b = bh >> 4, h = bh & 15;
#pragma unroll
  for (int i = 0; i < 4; ++i) {
    float inv = 1.0f / l_run[i];
    int q = qb + ((lane >> 4) << 2) + i;
#pragma unroll
    for (int n2 = 0; n2 < 4; ++n2) {
      int d = n2 * 16 + (lane & 15);
      AO[((size_t)b * Sn + q) * En + h * 64 + d] = (bf16_t)(O[n2][i] * inv);
    }
  }
}

// ---------------------------------------------------------------- launch
extern "C" void kernel_launch(void* const* d_in, const int* in_sizes, int n_in,
                              void* d_out, int out_size, void* d_ws, size_t ws_size,
                              hipStream_t stream) {
  const float* X     = (const float*)d_in[0];
  // d_in[1] = mask (causal; applied analytically)
  const float* W_qkv = (const float*)d_in[2];
  const float* b_qkv = (const float*)d_in[3];
  const float* W_o   = (const float*)d_in[4];
  const float* b_o   = (const float*)d_in[5];
  float* out = (float*)d_out;

  char* ws = (char*)d_ws;
  bf16_t* Xb  = (bf16_t*)(ws);
  bf16_t* WqT = (bf16_t*)(ws + 8388608);
  bf16_t* WoT = (bf16_t*)(ws + 14680064);
  bf16_t* Qb  = (bf16_t*)(ws + 16777216);
  bf16_t* Kb  = (bf16_t*)(ws + 25165824);
  bf16_t* Vb  = (bf16_t*)(ws + 33554432);
  bf16_t* Vt  = (bf16_t*)(ws + 41943040);
  bf16_t* AO  = (bf16_t*)(ws + 50331648);

  convert_f32_bf16<<<4096, 256, 0, stream>>>(X, Xb, Bn * Sn * En);
  transpose_conv<<<dim3(96, 32), 256, 0, stream>>>(W_qkv, WqT, 1024, 3072);
  transpose_conv<<<dim3(32, 32), 256, 0, stream>>>(W_o, WoT, 1024, 1024);
  gemm_qkv<<<dim3(24, 32), 256, 0, stream>>>(Xb, WqT, b_qkv, Qb, Kb, Vb);
  transpose_v<<<dim3(32, 32), 256, 0, stream>>>(Vb, Vt);
  attn_fwd<<<dim3(32, 32), 256, 0, stream>>>(Qb, Kb, Vt, AO);
  gemm_out<<<dim3(8, 32), 256, 0, stream>>>(AO, WoT, b_o, out);
}

// Round 5
// 239.321 us; speedup vs baseline: 1.3168x; 1.1086x over previous
//
#include <hip/hip_runtime.h>
#include <hip/hip_bf16.h>
#include <cstdint>
#include <cstddef>

typedef __bf16 bf16_t;
typedef __attribute__((ext_vector_type(8))) __bf16 bf16x8;
typedef __attribute__((ext_vector_type(4))) __bf16 bf16x4;
typedef __attribute__((ext_vector_type(4))) float f32x4;

#define AS1 __attribute__((address_space(1)))
#define AS3 __attribute__((address_space(3)))

static constexpr int Bn = 2, Sn = 2048, En = 1024, Hn = 16, Dn = 64;

// ---------------------------------------------------------------- convert X
__global__ __launch_bounds__(256) void convert_f32_bf16(
    const float* __restrict__ in, bf16_t* __restrict__ out, int n) {
  int i = (blockIdx.x * 256 + threadIdx.x) * 4;
  if (i < n) {
    float4 v = *(const float4*)(in + i);
    bf16x4 o;
    o[0] = (bf16_t)v.x; o[1] = (bf16_t)v.y; o[2] = (bf16_t)v.z; o[3] = (bf16_t)v.w;
    *(bf16x4*)(out + i) = o;
  }
}

// ------------------------------------------- transpose fp32 [R][C] -> bf16 [C][R]
__global__ __launch_bounds__(256) void transpose_conv(
    const float* __restrict__ in, bf16_t* __restrict__ out, int R, int C) {
  __shared__ float tile[32][33];
  int bx = blockIdx.x * 32, by = blockIdx.y * 32;
  int tx = threadIdx.x & 31, ty = threadIdx.x >> 5;  // ty 0..7
#pragma unroll
  for (int i = 0; i < 32; i += 8)
    tile[ty + i][tx] = in[(size_t)(by + ty + i) * C + bx + tx];
  __syncthreads();
#pragma unroll
  for (int i = 0; i < 32; i += 8)
    out[(size_t)(bx + ty + i) * R + by + tx] = (bf16_t)tile[tx][ty + i];
}

// -------------------------------- V [bh][S][64] -> Vt [bh][64][S]  (bf16)
__global__ __launch_bounds__(256) void transpose_v(
    const bf16_t* __restrict__ V, bf16_t* __restrict__ Vt) {
  __shared__ ushort tile[64][65];
  int bh = blockIdx.y, s0 = blockIdx.x * 64;
  int t = threadIdx.x;
  const ushort* src = (const ushort*)(V + ((size_t)bh * Sn + s0) * 64);
#pragma unroll
  for (int p = 0; p < 4; ++p) {
    int s = p * 16 + (t >> 4);
    int c = (t & 15) * 4;
    ushort4 v = *(const ushort4*)(src + (size_t)s * 64 + c);
    tile[s][c] = v.x; tile[s][c + 1] = v.y; tile[s][c + 2] = v.z; tile[s][c + 3] = v.w;
  }
  __syncthreads();
  ushort* dst = (ushort*)(Vt + ((size_t)bh * 64) * Sn + s0);
#pragma unroll
  for (int p = 0; p < 4; ++p) {
    int d = p * 16 + (t >> 4);
    int c = (t & 15) * 4;  // s offset within tile
    ushort4 v;
    v.x = tile[c][d]; v.y = tile[c + 1][d]; v.z = tile[c + 2][d]; v.w = tile[c + 3][d];
    *(ushort4*)(dst + (size_t)d * Sn + c) = v;
  }
}

// ---------------------------------------------------------------- GEMM core
// C = A[M][K] · Bt[N][K]^T. 128x128 tile, BK=32, 256 threads (2x2 waves of
// 64x64). global_load_lds width-16 staging; chunk XOR-swizzle (rule #21):
// LDS[row][chunk] holds global chunk (chunk ^ (row&3)); read applies same XOR.
template <int K_>
__device__ __forceinline__ void gemm_core(
    const bf16_t* __restrict__ A, const bf16_t* __restrict__ Bt,
    f32x4 (&acc)[4][4], int& col0, int& row0) {
  __shared__ bf16_t As[2][128 * 32];
  __shared__ bf16_t Bs[2][128 * 32];
  const int tid = threadIdx.x, lane = tid & 63, wid = tid >> 6;
  const int wm = wid >> 1, wn = wid & 1;
  const int m0 = blockIdx.y * 128, n0 = blockIdx.x * 128;
  const int KT = K_ / 32;

  auto stage = [&](bf16_t* as, bf16_t* bs, int kt) {
    int csw = ((lane & 3) ^ ((lane >> 2) & 3)) * 8;
#pragma unroll
    for (int j = 0; j < 2; ++j) {
      int r0 = wid * 32 + j * 16;
      const bf16_t* ga = A + (size_t)(m0 + r0 + (lane >> 2)) * K_ + kt * 32 + csw;
      __builtin_amdgcn_global_load_lds((const AS1 void*)ga, (AS3 void*)(as + r0 * 32), 16, 0, 0);
      const bf16_t* gb = Bt + (size_t)(n0 + r0 + (lane >> 2)) * K_ + kt * 32 + csw;
      __builtin_amdgcn_global_load_lds((const AS1 void*)gb, (AS3 void*)(bs + r0 * 32), 16, 0, 0);
    }
  };
  auto compute = [&](const bf16_t* as, const bf16_t* bs) {
    bf16x8 af[4], bfr[4];
    uint32_t swz = (uint32_t)(((lane >> 4) ^ (lane & 3)) << 4);
#pragma unroll
    for (int mi = 0; mi < 4; ++mi) {
      uint32_t row = (uint32_t)(wm * 64 + mi * 16 + (lane & 15));
      af[mi] = *(const bf16x8*)((const char*)as + row * 64 + swz);
    }
#pragma unroll
    for (int ni = 0; ni < 4; ++ni) {
      uint32_t row = (uint32_t)(wn * 64 + ni * 16 + (lane & 15));
      bfr[ni] = *(const bf16x8*)((const char*)bs + row * 64 + swz);
    }
#pragma unroll
    for (int mi = 0; mi < 4; ++mi)
#pragma unroll
      for (int ni = 0; ni < 4; ++ni)
        acc[mi][ni] = __builtin_amdgcn_mfma_f32_16x16x32_bf16(af[mi], bfr[ni], acc[mi][ni], 0, 0, 0);
  };

  stage(As[0], Bs[0], 0);
  __syncthreads();
  int cur = 0;
  for (int kt = 0; kt < KT - 1; ++kt) {
    stage(As[cur ^ 1], Bs[cur ^ 1], kt + 1);
    compute(As[cur], Bs[cur]);
    __syncthreads();
    cur ^= 1;
  }
  compute(As[cur], Bs[cur]);
  col0 = n0 + wn * 64 + (lane & 15);
  row0 = m0 + wm * 64 + ((lane >> 4) << 2);
}

__global__ __launch_bounds__(256) void gemm_qkv(
    const bf16_t* __restrict__ A, const bf16_t* __restrict__ Bt,
    const float* __restrict__ bias, bf16_t* __restrict__ Qb,
    bf16_t* __restrict__ Kb, bf16_t* __restrict__ Vb) {
  f32x4 acc[4][4] = {};
  int col0, row0;
  gemm_core<1024>(A, Bt, acc, col0, row0);
#pragma unroll
  for (int ni = 0; ni < 4; ++ni) {
    int n = col0 + ni * 16;
    float bv = bias[n];
    int which = n >> 10, nn = n & 1023;
    int h = nn >> 6, dd = nn & 63;
    bf16_t* dst = which == 0 ? Qb : (which == 1 ? Kb : Vb);
    float scl = which == 0 ? 0.125f : 1.0f;  // fold 1/sqrt(64) into Q
#pragma unroll
    for (int mi = 0; mi < 4; ++mi)
#pragma unroll
      for (int i = 0; i < 4; ++i) {
        int m = row0 + mi * 16 + i;
        int b = m >> 11, s = m & 2047;
        float v = (acc[mi][ni][i] + bv) * scl;
        dst[(((size_t)b * Hn + h) * Sn + s) * 64 + dd] = (bf16_t)v;
      }
  }
}

__global__ __launch_bounds__(256) void gemm_out(
    const bf16_t* __restrict__ A, const bf16_t* __restrict__ Bt,
    const float* __restrict__ bias, float* __restrict__ out) {
  f32x4 acc[4][4] = {};
  int col0, row0;
  gemm_core<1024>(A, Bt, acc, col0, row0);
#pragma unroll
  for (int ni = 0; ni < 4; ++ni) {
    int n = col0 + ni * 16;
    float bv = bias[n];
#pragma unroll
    for (int mi = 0; mi < 4; ++mi)
#pragma unroll
      for (int i = 0; i < 4; ++i) {
        int m = row0 + mi * 16 + i;
        out[(size_t)m * En + n] = acc[mi][ni][i] + bv;
      }
  }
}

// -------------------------------------------------------- flash attention fwd
// grid (16, B*H). Causal pairing: block pr handles q_tiles {pr, 31-pr} =
// exactly 33 KV-tile iterations per block (perfect balance, no tail).
// 4 waves x 16 q-rows; KVBLK=64; K/V double-buffered via global_load_lds w16
// with pre-swizzled global source; prefetch crosses the segment boundary.
// Defer-max (T13, THR=8): skip O/l rescale when tile max growth <= 8.
__global__ __launch_bounds__(256) void attn_fwd(
    const bf16_t* __restrict__ Qb, const bf16_t* __restrict__ Kb,
    const bf16_t* __restrict__ Vt, bf16_t* __restrict__ AO) {
  __shared__ bf16_t Ks[2][64 * 64];
  __shared__ bf16_t Vs[2][64 * 64];
  __shared__ bf16_t Ps[4][16 * 64];
  const int tid = threadIdx.x, lane = tid & 63, wid = tid >> 6;
  const int bh = blockIdx.y;
  const int pr = blockIdx.x;  // pair index 0..15

  // stage K rows (kv) and V rows (d) for kv-tile t into buf: wave w covers
  // rows w*16..w*16+15 via 2 x global_load_lds (each 8 rows, 16B/lane),
  // source chunk pre-swizzled to match read-side XOR.
  const int rl = lane >> 3;     // row within 8-row group
  const int cp = lane & 7;      // physical 16B chunk
  auto issueKV = [&](int buf, int t) {
#pragma unroll
    for (int j = 0; j < 2; ++j) {
      int r = wid * 16 + j * 8 + rl;
      int sc = cp ^ (r & 7);    // source logical chunk (pre-swizzle)
      const bf16_t* gk = Kb + (((size_t)bh * Sn + t * 64 + r) << 6) + (sc << 3);
      __builtin_amdgcn_global_load_lds((const AS1 void*)gk,
          (AS3 void*)(&Ks[buf][wid * 1024 + j * 512]), 16, 0, 0);
      const bf16_t* gv = Vt + ((size_t)bh * 64 + r) * Sn + t * 64 + (sc << 3);
      __builtin_amdgcn_global_load_lds((const AS1 void*)gv,
          (AS3 void*)(&Vs[buf][wid * 1024 + j * 512]), 16, 0, 0);
    }
  };

  int buf = 0;
  issueKV(0, 0);

  for (int seg = 0; seg < 2; ++seg) {
    const int q_tile = seg ? 31 - pr : pr;
    const int nt = q_tile + 1;
    const int qb = q_tile * 64 + wid * 16;

    bf16x8 aq[2];
    {
      const bf16_t* qp = Qb + ((size_t)bh * Sn + qb + (lane & 15)) * 64 + ((lane >> 4) << 3);
      aq[0] = *(const bf16x8*)qp;
      aq[1] = *(const bf16x8*)(qp + 32);
    }
    f32x4 O[4] = {};
    float m_run[4], l_run[4];
#pragma unroll
    for (int i = 0; i < 4; ++i) { m_run[i] = -1e30f; l_run[i] = 0.f; }

    for (int t = 0; t < nt; ++t) {
      asm volatile("s_waitcnt vmcnt(0)" ::: "memory");
      __syncthreads();
      if (t + 1 < nt) issueKV(buf ^ 1, t + 1);
      else if (seg == 0) issueKV(buf ^ 1, 0);  // prefetch segment 1, tile 0
      const char* ksb = (const char*)Ks[buf];
      const char* vsb = (const char*)Vs[buf];
      // QK^T : S[16 q][64 kv]
      f32x4 sc[4];
#pragma unroll
      for (int ni = 0; ni < 4; ++ni) {
        int kvr = ni * 16 + (lane & 15);
        uint32_t o0 = (uint32_t)(kvr * 128 + ((lane >> 4) << 4)) ^ (uint32_t)((kvr & 7) << 4);
        uint32_t o1 = (uint32_t)(kvr * 128 + 64 + ((lane >> 4) << 4)) ^ (uint32_t)((kvr & 7) << 4);
        bf16x8 b0 = *(const bf16x8*)(ksb + o0);
        bf16x8 b1 = *(const bf16x8*)(ksb + o1);
        f32x4 z = {};
        z = __builtin_amdgcn_mfma_f32_16x16x32_bf16(aq[0], b0, z, 0, 0, 0);
        sc[ni] = __builtin_amdgcn_mfma_f32_16x16x32_bf16(aq[1], b1, z, 0, 0, 0);
      }
      if (t == nt - 1) {  // diagonal tile: causal mask
#pragma unroll
        for (int ni = 0; ni < 4; ++ni) {
          int kv = t * 64 + ni * 16 + (lane & 15);
#pragma unroll
          for (int i = 0; i < 4; ++i) {
            int q = qb + ((lane >> 4) << 2) + i;
            if (kv > q) sc[ni][i] = -1e30f;
          }
        }
      }
      // online softmax (row i lives at q = qb + (lane>>4)*4 + i)
      float mt[4];
#pragma unroll
      for (int i = 0; i < 4; ++i) {
        float v = fmaxf(fmaxf(sc[0][i], sc[1][i]), fmaxf(sc[2][i], sc[3][i]));
        v = fmaxf(v, __shfl_xor(v, 1));
        v = fmaxf(v, __shfl_xor(v, 2));
        v = fmaxf(v, __shfl_xor(v, 4));
        v = fmaxf(v, __shfl_xor(v, 8));
        mt[i] = v;
      }
      // defer-max: only rescale when some row grew by > 8
      int ok = (mt[0] <= m_run[0] + 8.f) && (mt[1] <= m_run[1] + 8.f) &&
               (mt[2] <= m_run[2] + 8.f) && (mt[3] <= m_run[3] + 8.f);
      if (!__all(ok)) {
#pragma unroll
        for (int i = 0; i < 4; ++i) {
          float mn = fmaxf(m_run[i], mt[i]);
          float s = __expf(m_run[i] - mn);
          m_run[i] = mn;
          l_run[i] *= s;
#pragma unroll
          for (int n2 = 0; n2 < 4; ++n2) O[n2][i] *= s;
        }
      }
      float rs[4] = {0.f, 0.f, 0.f, 0.f};
      char* pw = (char*)Ps[wid];
#pragma unroll
      for (int ni = 0; ni < 4; ++ni)
#pragma unroll
        for (int i = 0; i < 4; ++i) {
          float p = __expf(sc[ni][i] - m_run[i]);
          rs[i] += p;
          int r = ((lane >> 4) << 2) + i;
          uint32_t off = (uint32_t)(r * 128 + (ni * 16 + (lane & 15)) * 2) ^ (uint32_t)((r & 7) << 4);
          *(bf16_t*)(pw + off) = (bf16_t)p;
        }
#pragma unroll
      for (int i = 0; i < 4; ++i) {
        float v = rs[i];
        v += __shfl_xor(v, 1);
        v += __shfl_xor(v, 2);
        v += __shfl_xor(v, 4);
        v += __shfl_xor(v, 8);
        l_run[i] += v;
      }
      asm volatile("s_waitcnt lgkmcnt(0)" ::: "memory");
      __builtin_amdgcn_sched_barrier(0);
      // PV : O += P[16 q][64 kv] x V[64 kv][64 d]
      bf16x8 pa[2];
      {
        int r = lane & 15;
        uint32_t o0 = (uint32_t)(r * 128 + ((lane >> 4) << 4)) ^ (uint32_t)((r & 7) << 4);
        uint32_t o1 = (uint32_t)(r * 128 + 64 + ((lane >> 4) << 4)) ^ (uint32_t)((r & 7) << 4);
        pa[0] = *(const bf16x8*)((const char*)pw + o0);
        pa[1] = *(const bf16x8*)((const char*)pw + o1);
      }
#pragma unroll
      for (int n2 = 0; n2 < 4; ++n2) {
        int dr = n2 * 16 + (lane & 15);
        uint32_t o0 = (uint32_t)(dr * 128 + ((lane >> 4) << 4)) ^ (uint32_t)((dr & 7) << 4);
        uint32_t o1 = (uint32_t)(dr * 128 + 64 + ((lane >> 4) << 4)) ^ (uint32_t)((dr & 7) << 4);
        bf16x8 v0 = *(const bf16x8*)(vsb + o0);
        bf16x8 v1 = *(const bf16x8*)(vsb + o1);
        O[n2] = __builtin_amdgcn_mfma_f32_16x16x32_bf16(pa[0], v0, O[n2], 0, 0, 0);
        O[n2] = __builtin_amdgcn_mfma_f32_16x16x32_bf16(pa[1], v1, O[n2], 0, 0, 0);
      }
      buf ^= 1;
    }
    // epilogue: AO[b][s][h*64+d] bf16
    int b = bh >> 4, h = bh & 15;
#pragma unroll
    for (int i = 0; i < 4; ++i) {
      float inv = 1.0f / l_run[i];
      int q = qb + ((lane >> 4) << 2) + i;
#pragma unroll
      for (int n2 = 0; n2 < 4; ++n2) {
        int d = n2 * 16 + (lane & 15);
        AO[((size_t)b * Sn + q) * En + h * 64 + d] = (bf16_t)(O[n2][i] * inv);
      }
    }
  }
}

// ---------------------------------------------------------------- launch
extern "C" void kernel_launch(void* const* d_in, const int* in_sizes, int n_in,
                              void* d_out, int out_size, void* d_ws, size_t ws_size,
                              hipStream_t stream) {
  const float* X     = (const float*)d_in[0];
  // d_in[1] = mask (causal; applied analytically)
  const float* W_qkv = (const float*)d_in[2];
  const float* b_qkv = (const float*)d_in[3];
  const float* W_o   = (const float*)d_in[4];
  const float* b_o   = (const float*)d_in[5];
  float* out = (float*)d_out;

  char* ws = (char*)d_ws;
  bf16_t* Xb  = (bf16_t*)(ws);
  bf16_t* WqT = (bf16_t*)(ws + 8388608);
  bf16_t* WoT = (bf16_t*)(ws + 14680064);
  bf16_t* Qb  = (bf16_t*)(ws + 16777216);
  bf16_t* Kb  = (bf16_t*)(ws + 25165824);
  bf16_t* Vb  = (bf16_t*)(ws + 33554432);
  bf16_t* Vt  = (bf16_t*)(ws + 41943040);
  bf16_t* AO  = (bf16_t*)(ws + 50331648);

  convert_f32_bf16<<<4096, 256, 0, stream>>>(X, Xb, Bn * Sn * En);
  transpose_conv<<<dim3(96, 32), 256, 0, stream>>>(W_qkv, WqT, 1024, 3072);
  transpose_conv<<<dim3(32, 32), 256, 0, stream>>>(W_o, WoT, 1024, 1024);
  gemm_qkv<<<dim3(24, 32), 256, 0, stream>>>(Xb, WqT, b_qkv, Qb, Kb, Vb);
  transpose_v<<<dim3(32, 32), 256, 0, stream>>>(Vb, Vt);
  attn_fwd<<<dim3(16, 32), 256, 0, stream>>>(Qb, Kb, Vt, AO);
  gemm_out<<<dim3(8, 32), 256, 0, stream>>>(AO, WoT, b_o, out);
}